// Round 1
// 346.355 us; speedup vs baseline: 1.2160x; 1.2160x over previous
//
#include <hip/hip_runtime.h>
#include <hip/hip_bf16.h>

#define FEAT 128
#define OUTF 64
#define BBITS 10          // nodes per bucket = 1024
#define NPB (1 << BBITS)
#define BCAP 20480        // mean 16384 edges/bucket, sigma ~127 -> +32 sigma
#define L1_CHUNK 8192

typedef __attribute__((ext_vector_type(8))) short short8;   // 8 bf16 = 4 VGPRs (MFMA A/B frag)
typedef __attribute__((ext_vector_type(4))) float floatx4;  // MFMA C/D frag

// ---- bf16 helpers (packed pair in a 32-bit word, little-endian: lo16 = even elem) ----
__device__ inline float bflo(unsigned p) { union { unsigned u; float f; } c; c.u = p << 16;        return c.f; }
__device__ inline float bfhi(unsigned p) { union { unsigned u; float f; } c; c.u = p & 0xffff0000u; return c.f; }
__device__ inline unsigned rne16(float v) {   // fp32 -> bf16 bits, round-nearest-even
    union { float f; unsigned u; } c; c.f = v;
    return (c.u + 0x7fffu + ((c.u >> 16) & 1u)) >> 16;
}
__device__ inline unsigned pack2bf(float a, float b) { return rne16(a) | (rne16(b) << 16); }

// ---------------- dtype sniffing ----------------
// flags[0]=1 iff x is packed bf16; flags[1]=1 iff edge_index is int64; flags[2]=1 iff W is packed bf16.
__global__ void sniff(const unsigned* __restrict__ x, const unsigned* __restrict__ ei,
                      const unsigned* __restrict__ Wv, int* __restrict__ flags) {
    __shared__ int s_x, s_z, s_w;
    if (threadIdx.x == 0) { s_x = 0; s_z = 0; s_w = 0; }
    __syncthreads();
    unsigned lx = x[threadIdx.x] & 0xffffu;
    unsigned ex = (lx >> 7) & 0xffu;
    if (lx == 0u || (ex >= 100u && ex <= 140u)) atomicAdd(&s_x, 1);
    unsigned lw = Wv[threadIdx.x] & 0xffffu;
    unsigned ew = (lw >> 7) & 0xffu;
    if (lw == 0u || (ew >= 100u && ew <= 140u)) atomicAdd(&s_w, 1);
    if (ei[2 * threadIdx.x + 1] == 0u) atomicAdd(&s_z, 1);
    __syncthreads();
    if (threadIdx.x == 0) {
        flags[0] = (s_x >= 230) ? 1 : 0;
        flags[1] = (s_z >= 250) ? 1 : 0;
        flags[2] = (s_w >= 230) ? 1 : 0;
    }
}

__device__ inline int edge_row(const int* __restrict__ ei, int E, int e, int w64) {
    return w64 ? ei[2 * e] : ei[e];
}
__device__ inline int edge_col(const int* __restrict__ ei, int E, int e, int w64) {
    return w64 ? ei[2 * (E + e)] : ei[E + e];
}

// ---------------- CSR build: two-level, LDS-binned ----------------

__global__ void zero_ints(int* __restrict__ a, int m) {
    int i = blockIdx.x * blockDim.x + threadIdx.x;
    if (i < m) a[i] = 0;
}

// level 1: chunk of 8192 edges per block -> LDS bin-sort by (dst>>10) -> dense copy-out.
// packed word: (dst_local[10] << 17) | src_row[17]   (n < 2^17)
__global__ void __launch_bounds__(256)
level1_bin(const int* __restrict__ ei, int E, int* __restrict__ bcursor,
           unsigned* __restrict__ bucket, const int* __restrict__ flags, int nbuck) {
    __shared__ unsigned elds[L1_CHUNK];
    __shared__ unsigned char ebin[L1_CHUNK];
    __shared__ int hist[128], binstart[128], cur[128], ticket[128];
    int t = threadIdx.x;
    int base = blockIdx.x * L1_CHUNK;
    int cnt = min(E - base, L1_CHUNK);
    int w64 = flags[1];

    if (t < 128) hist[t] = 0;
    __syncthreads();
    for (int k = t; k < cnt; k += 256)
        atomicAdd(&hist[edge_col(ei, E, base + k, w64) >> BBITS], 1);
    __syncthreads();
    if (t < 128) binstart[t] = hist[t];
    __syncthreads();
    for (int off = 1; off < 128; off <<= 1) {
        int v = (t < 128 && t >= off) ? binstart[t - off] : 0;
        __syncthreads();
        if (t < 128) binstart[t] += v;
        __syncthreads();
    }
    if (t < 128) { int ex = binstart[t] - hist[t]; cur[t] = ex; binstart[t] = ex; }
    __syncthreads();
    for (int k = t; k < cnt; k += 256) {
        int e = base + k;
        int c = edge_col(ei, E, e, w64);
        int r = edge_row(ei, E, e, w64);
        int b = c >> BBITS;
        int pos = atomicAdd(&cur[b], 1);
        elds[pos] = ((unsigned)(c & (NPB - 1)) << 17) | (unsigned)r;
        ebin[pos] = (unsigned char)b;
    }
    __syncthreads();
    if (t < 128) {
        int h = hist[t];
        ticket[t] = (t < nbuck && h > 0) ? atomicAdd(&bcursor[t], h) : 0;
    }
    __syncthreads();
    for (int k = t; k < cnt; k += 256) {
        unsigned w = elds[k];
        int b = ebin[k];
        int dst = ticket[b] + (k - binstart[b]);
        if (dst < BCAP) bucket[(size_t)b * BCAP + dst] = w;
    }
}

// single block: exclusive scan of nb (<=512) bucket counts; total -> offsets[n]
__global__ void scan_bsums(const int* __restrict__ bsum, int nb,
                           int* __restrict__ boff, int* __restrict__ total_out) {
    __shared__ int sdata[512];
    int tid = threadIdx.x;
    int v = (tid < nb) ? bsum[tid] : 0;
    sdata[tid] = v;
    __syncthreads();
    for (int off = 1; off < 512; off <<= 1) {
        int t = (tid >= off) ? sdata[tid - off] : 0;
        __syncthreads();
        sdata[tid] += t;
        __syncthreads();
    }
    if (tid < nb) boff[tid] = sdata[tid] - v;       // exclusive
    if (tid == 511) *total_out = sdata[511];        // grand total -> offsets[n]
}

// level 2: one workgroup per bucket (1024 nodes). LDS hist -> offsets+dinv; LDS cursor
// scatter into ~65KB contiguous csr window.
__global__ void __launch_bounds__(256)
level2_csr(const unsigned* __restrict__ bucket, const int* __restrict__ bcursor,
           const int* __restrict__ boff, int n,
           int* __restrict__ offsets, float* __restrict__ dinv, int* __restrict__ csr) {
    __shared__ int hist[NPB];
    __shared__ int nodeoff[NPB];
    __shared__ int wsum[256];
    int b = blockIdx.x;
    int t = threadIdx.x;
    int nbeg = b << BBITS;
    int cnt = min(bcursor[b], BCAP);
    int base = boff[b];
    const unsigned* __restrict__ bk = bucket + (size_t)b * BCAP;

    for (int j = t; j < NPB; j += 256) hist[j] = 0;
    __syncthreads();
    for (int e = t; e < cnt; e += 256) atomicAdd(&hist[bk[e] >> 17], 1);
    __syncthreads();
    int h0 = hist[4 * t], h1 = hist[4 * t + 1], h2 = hist[4 * t + 2], h3 = hist[4 * t + 3];
    int s = h0 + h1 + h2 + h3;
    wsum[t] = s;
    __syncthreads();
    for (int off = 1; off < 256; off <<= 1) {
        int v = (t >= off) ? wsum[t - off] : 0;
        __syncthreads();
        wsum[t] += v;
        __syncthreads();
    }
    int p = base + wsum[t] - s;                 // exclusive offset for node 4t
    nodeoff[4 * t]     = p;
    nodeoff[4 * t + 1] = p + h0;
    nodeoff[4 * t + 2] = p + h0 + h1;
    nodeoff[4 * t + 3] = p + h0 + h1 + h2;
    int hs[4] = {h0, h1, h2, h3};
#pragma unroll
    for (int j = 0; j < 4; ++j) {
        int node = nbeg + 4 * t + j;
        if (node < n) {
            offsets[node] = nodeoff[4 * t + j];
            dinv[node] = rsqrtf((float)(hs[j] + 1));   // +1 self-loop; deg>=1 always
        }
    }
    __syncthreads();
    for (int j = t; j < NPB; j += 256) hist[j] = 0;    // reuse as cursors
    __syncthreads();
    for (int e = t; e < cnt; e += 256) {
        unsigned w = bk[e];
        int l = w >> 17;
        int pos = nodeoff[l] + atomicAdd(&hist[l], 1);
        csr[pos] = (int)(w & 0x1FFFFu);
    }
}

// ---------------- W -> packed bf16 ----------------
__global__ void convert_w(const void* __restrict__ Wv, unsigned* __restrict__ Wp,
                          int total_pairs, const int* __restrict__ flags) {
    int idx = blockIdx.x * blockDim.x + threadIdx.x;
    if (idx >= total_pairs) return;
    if (flags[2]) {
        Wp[idx] = ((const unsigned*)Wv)[idx];
    } else {
        float2 v = ((const float2*)Wv)[idx];
        Wp[idx] = pack2bf(v.x, v.y);
    }
}

// ---------------- up-front projection: y[node][64] = dinv[node] * (x_row . W_col) ----------------
// A = W rows (M-tile per wave: outcols wave*16..+15), B = node rows (N = 16 nodes/block).
// D row=(lane>>4)*4+reg -> outcol, D col=lane&15 -> node  [m89-verified C/D layout].
// x is converted fp32->bf16 in an LDS tile (stride 68 dwords: 16B-aligned rows, 2-way banks = free).
__global__ void __launch_bounds__(256)
project_mfma(const void* __restrict__ xv, const unsigned* __restrict__ Wp,
             const float* __restrict__ dinv, unsigned* __restrict__ y,
             int n, const int* __restrict__ flags) {
    __shared__ unsigned xs[16][68];
    int t = threadIdx.x;
    int wave = t >> 6;               // outcol tile 0..3
    int lane = t & 63;
    int m16  = lane & 15;
    int quad = lane >> 4;
    int row0 = blockIdx.x * 16;
    if (row0 >= n) return;
    int fx = flags[0];

    // stage 16 node rows as packed bf16 into LDS (converted once, shared by 4 waves)
    for (int idx = t; idx < 16 * 64; idx += 256) {
        int r = idx >> 6, p = idx & 63;
        int node = min(row0 + r, n - 1);
        unsigned w;
        if (fx) {
            w = ((const unsigned*)xv)[(size_t)node * 64 + p];
        } else {
            float2 v = ((const float2*)xv)[(size_t)node * 64 + p];
            w = pack2bf(v.x, v.y);
        }
        xs[r][p] = w;
    }
    __syncthreads();

    const uint4* __restrict__ Arow = (const uint4*)(Wp + (size_t)(wave * 16 + m16) * 64);
    floatx4 acc = {0.f, 0.f, 0.f, 0.f};
#pragma unroll
    for (int kc = 0; kc < 4; ++kc) {
        union { uint4 u; short8 s; } a, b;
        a.u = Arow[kc * 4 + quad];
        b.u = *(const uint4*)&xs[m16][(kc * 4 + quad) * 4];
        acc = __builtin_amdgcn_mfma_f32_16x16x32_bf16(a.s, b.s, acc, 0, 0, 0);
    }
    int node = row0 + m16;
    if (node < n) {
        float di = dinv[node];
        uint2 w;
        w.x = pack2bf(di * acc[0], di * acc[1]);
        w.y = pack2bf(di * acc[2], di * acc[3]);
        *(uint2*)(y + (size_t)node * 32 + wave * 8 + quad * 2) = w;   // outcols wave*16+quad*4..+3
    }
}

// ---------------- propagation on 64-feat pre-scaled rows ----------------
// g[j] = dinv[j]*h[j] is stored; per hop: sum_{j in N(i)+self} g[j], then
//   mode 0: g_out = di^2 * sum (bf16)      mode 1: h_out = di*sum + b (fp32 to d_out)
// wave = 1 node; half-wave (32 lanes) = 1 edge (128B row), so 2 edges per load inst.
__global__ void __launch_bounds__(256)
propagate64(const unsigned* __restrict__ hin, const int* __restrict__ offsets,
            const int* __restrict__ csr, const float* __restrict__ dinv,
            void* __restrict__ outv, const void* __restrict__ bv,
            int n, int mode, const int* __restrict__ flags) {
    int wave = threadIdx.x >> 6;
    int lane = threadIdx.x & 63;
    int hi   = lane >> 5;            // which half-wave
    int l32  = lane & 31;            // dword (feat pair) within row
    int i = blockIdx.x * 4 + wave;
    if (i >= n) return;
    int beg = offsets[i];
    int end = offsets[i + 1];
    float ax = 0.f, ay = 0.f;
    int k = beg + hi;                // this half handles edges beg+hi, beg+hi+2, ...
    for (; k + 6 < end; k += 8) {    // 8 edges per wave-iteration (4 per half)
        int s0 = csr[k], s1 = csr[k + 2], s2 = csr[k + 4], s3 = csr[k + 6];
        unsigned p0 = hin[(size_t)s0 * 32 + l32];
        unsigned p1 = hin[(size_t)s1 * 32 + l32];
        unsigned p2 = hin[(size_t)s2 * 32 + l32];
        unsigned p3 = hin[(size_t)s3 * 32 + l32];
        ax += bflo(p0); ay += bfhi(p0);
        ax += bflo(p1); ay += bfhi(p1);
        ax += bflo(p2); ay += bfhi(p2);
        ax += bflo(p3); ay += bfhi(p3);
    }
    for (; k < end; k += 2) {
        int s = csr[k];
        unsigned p = hin[(size_t)s * 32 + l32];
        ax += bflo(p); ay += bfhi(p);
    }
    // combine halves, then add self-loop term once
    ax += __shfl_xor(ax, 32);
    ay += __shfl_xor(ay, 32);
    unsigned ps = hin[(size_t)i * 32 + l32];
    ax += bflo(ps); ay += bfhi(ps);
    float di = dinv[i];
    if (hi == 0) {
        if (mode == 0) {
            float s = di * di;
            ((unsigned*)outv)[(size_t)i * 32 + l32] = pack2bf(s * ax, s * ay);
        } else {
            float b0, b1;
            if (flags[2]) {
                const unsigned short* bb = (const unsigned short*)bv;
                union { unsigned u; float f; } c0, c1;
                c0.u = (unsigned)bb[2 * l32] << 16;
                c1.u = (unsigned)bb[2 * l32 + 1] << 16;
                b0 = c0.f; b1 = c1.f;
            } else {
                const float* bf = (const float*)bv;
                b0 = bf[2 * l32]; b1 = bf[2 * l32 + 1];
            }
            float2 o;
            o.x = di * ax + b0;
            o.y = di * ay + b1;
            ((float2*)outv)[(size_t)i * 32 + l32] = o;
        }
    }
}

// ---------------- launch ----------------

extern "C" void kernel_launch(void* const* d_in, const int* in_sizes, int n_in,
                              void* d_out, int out_size, void* d_ws, size_t ws_size,
                              hipStream_t stream) {
    const void* x  = d_in[0];
    const int*  ei = (const int*)d_in[1];
    const void* W  = d_in[2];
    const void* b  = d_in[3];
    float* out = (float*)d_out;              // fp32 output

    const int n = in_sizes[0] / FEAT;        // 100000
    const int E = in_sizes[1] / 2;           // 1600000
    const int nbuck = (n + NPB - 1) >> BBITS;   // 98 <= 128

    // workspace layout (256B-aligned slabs)
    char* ws = (char*)d_ws;
    size_t off = 0;
    auto alloc = [&](size_t bytes) {
        void* p = ws + off;
        off = (off + bytes + 255) & ~(size_t)255;
        return p;
    };
    unsigned* y       = (unsigned*)alloc((size_t)n * 32 * sizeof(unsigned));  // 64-feat bf16 rows
    unsigned* hA      = (unsigned*)alloc((size_t)n * 32 * sizeof(unsigned));
    unsigned* Wp      = (unsigned*)alloc((size_t)OUTF * (FEAT / 2) * sizeof(unsigned));
    int*      offsets = (int*)alloc((size_t)(n + 1) * sizeof(int));
    float*    dinv    = (float*)alloc((size_t)n * sizeof(float));
    int*      csr     = (int*)alloc((size_t)E * sizeof(int));
    unsigned* bucket  = (unsigned*)alloc((size_t)nbuck * BCAP * sizeof(unsigned));
    int*      bcursor = (int*)alloc((size_t)nbuck * sizeof(int));
    int*      boff    = (int*)alloc((size_t)nbuck * sizeof(int));
    int*      flags   = (int*)alloc(3 * sizeof(int));

    // dtype sniff (device-side; graph-safe)
    sniff<<<1, 256, 0, stream>>>((const unsigned*)x, (const unsigned*)ei,
                                 (const unsigned*)W, flags);

    // CSR build: LDS-binned two-level
    zero_ints<<<1, 256, 0, stream>>>(bcursor, nbuck);
    level1_bin<<<(E + L1_CHUNK - 1) / L1_CHUNK, 256, 0, stream>>>(ei, E, bcursor, bucket,
                                                                  flags, nbuck);
    scan_bsums<<<1, 512, 0, stream>>>(bcursor, nbuck, boff, &offsets[n]);
    level2_csr<<<nbuck, 256, 0, stream>>>(bucket, bcursor, boff, n, offsets, dinv, csr);

    // W -> bf16 packed
    convert_w<<<(OUTF * FEAT / 2 + 255) / 256, 256, 0, stream>>>(W, Wp, OUTF * FEAT / 2, flags);

    // project first: y = dinv * (x @ W^T)   [(A^3 x) W^T == A^3 (x W^T)]
    project_mfma<<<(n + 15) / 16, 256, 0, stream>>>(x, Wp, dinv, y, n, flags);

    // 3 hops on 64-feat rows: y -> hA -> y -> out (last hop adds bias, writes fp32)
    const int propBlocks = (n + 3) / 4;      // 4 waves/block, 1 node/wave
    propagate64<<<propBlocks, 256, 0, stream>>>(y,  offsets, csr, dinv, hA,  b, n, 0, flags);
    propagate64<<<propBlocks, 256, 0, stream>>>(hA, offsets, csr, dinv, y,   b, n, 0, flags);
    propagate64<<<propBlocks, 256, 0, stream>>>(y,  offsets, csr, dinv, out, b, n, 1, flags);
}

// Round 2
// 303.667 us; speedup vs baseline: 1.3869x; 1.1406x over previous
//
#include <hip/hip_runtime.h>
#include <hip/hip_bf16.h>

#define FEAT 128
#define OUTF 64
#define BBITS 9           // nodes per bucket = 512
#define NPB (1 << BBITS)
#define NBIN 256          // level-1 hist arrays (nbuck = 196 <= 256)
#define BCAP 10240        // mean 8163 edges/bucket, sigma ~90 -> +23 sigma
#define L1_CHUNK 4096

typedef __attribute__((ext_vector_type(8))) short short8;   // 8 bf16 = 4 VGPRs (MFMA A/B frag)
typedef __attribute__((ext_vector_type(4))) float floatx4;  // MFMA C/D frag

// ---- bf16 helpers (packed pair in a 32-bit word, little-endian: lo16 = even elem) ----
__device__ inline float bflo(unsigned p) { union { unsigned u; float f; } c; c.u = p << 16;        return c.f; }
__device__ inline float bfhi(unsigned p) { union { unsigned u; float f; } c; c.u = p & 0xffff0000u; return c.f; }
__device__ inline unsigned rne16(float v) {   // fp32 -> bf16 bits, round-nearest-even
    union { float f; unsigned u; } c; c.f = v;
    return (c.u + 0x7fffu + ((c.u >> 16) & 1u)) >> 16;
}
__device__ inline unsigned pack2bf(float a, float b) { return rne16(a) | (rne16(b) << 16); }

// ---------------- dtype sniffing ----------------
// flags[0]=1 iff x is packed bf16; flags[1]=1 iff edge_index is int64; flags[2]=1 iff W is packed bf16.
__global__ void sniff(const unsigned* __restrict__ x, const unsigned* __restrict__ ei,
                      const unsigned* __restrict__ Wv, int* __restrict__ flags) {
    __shared__ int s_x, s_z, s_w;
    if (threadIdx.x == 0) { s_x = 0; s_z = 0; s_w = 0; }
    __syncthreads();
    unsigned lx = x[threadIdx.x] & 0xffffu;
    unsigned ex = (lx >> 7) & 0xffu;
    if (lx == 0u || (ex >= 100u && ex <= 140u)) atomicAdd(&s_x, 1);
    unsigned lw = Wv[threadIdx.x] & 0xffffu;
    unsigned ew = (lw >> 7) & 0xffu;
    if (lw == 0u || (ew >= 100u && ew <= 140u)) atomicAdd(&s_w, 1);
    if (ei[2 * threadIdx.x + 1] == 0u) atomicAdd(&s_z, 1);
    __syncthreads();
    if (threadIdx.x == 0) {
        flags[0] = (s_x >= 230) ? 1 : 0;
        flags[1] = (s_z >= 250) ? 1 : 0;
        flags[2] = (s_w >= 230) ? 1 : 0;
    }
}

__device__ inline int edge_row(const int* __restrict__ ei, int E, int e, int w64) {
    return w64 ? ei[2 * e] : ei[e];
}
__device__ inline int edge_col(const int* __restrict__ ei, int E, int e, int w64) {
    return w64 ? ei[2 * (E + e)] : ei[E + e];
}

// ---------------- CSR build: two-level, LDS-binned ----------------

__global__ void zero_ints(int* __restrict__ a, int m) {
    int i = blockIdx.x * blockDim.x + threadIdx.x;
    if (i < m) a[i] = 0;
}

// level 1: chunk of 4096 edges per block -> LDS bin-sort by (dst>>9) -> dense copy-out.
// packed word: (dst_local[9] << 17) | src_row[17]   (n < 2^17)
__global__ void __launch_bounds__(256)
level1_bin(const int* __restrict__ ei, int E, int* __restrict__ bcursor,
           unsigned* __restrict__ bucket, const int* __restrict__ flags, int nbuck) {
    __shared__ unsigned elds[L1_CHUNK];
    __shared__ unsigned char ebin[L1_CHUNK];
    __shared__ int hist[NBIN], binstart[NBIN], cur[NBIN], ticket[NBIN];
    int t = threadIdx.x;
    int base = blockIdx.x * L1_CHUNK;
    int cnt = min(E - base, L1_CHUNK);
    int w64 = flags[1];

    hist[t] = 0;
    __syncthreads();
    for (int k = t; k < cnt; k += 256)
        atomicAdd(&hist[edge_col(ei, E, base + k, w64) >> BBITS], 1);
    __syncthreads();
    binstart[t] = hist[t];
    __syncthreads();
    for (int off = 1; off < NBIN; off <<= 1) {
        int v = (t >= off) ? binstart[t - off] : 0;
        __syncthreads();
        binstart[t] += v;
        __syncthreads();
    }
    { int ex = binstart[t] - hist[t]; cur[t] = ex; binstart[t] = ex; }
    __syncthreads();
    for (int k = t; k < cnt; k += 256) {
        int e = base + k;
        int c = edge_col(ei, E, e, w64);
        int r = edge_row(ei, E, e, w64);
        int b = c >> BBITS;
        int pos = atomicAdd(&cur[b], 1);
        elds[pos] = ((unsigned)(c & (NPB - 1)) << 17) | (unsigned)r;
        ebin[pos] = (unsigned char)b;
    }
    __syncthreads();
    {
        int h = hist[t];
        ticket[t] = (t < nbuck && h > 0) ? atomicAdd(&bcursor[t], h) : 0;
    }
    __syncthreads();
    for (int k = t; k < cnt; k += 256) {
        unsigned w = elds[k];
        int b = ebin[k];
        int dst = ticket[b] + (k - binstart[b]);
        if (dst < BCAP) bucket[(size_t)b * BCAP + dst] = w;
    }
}

// single block: exclusive scan of nb (<=512) bucket counts; total -> offsets[n]
__global__ void scan_bsums(const int* __restrict__ bsum, int nb,
                           int* __restrict__ boff, int* __restrict__ total_out) {
    __shared__ int sdata[512];
    int tid = threadIdx.x;
    int v = (tid < nb) ? bsum[tid] : 0;
    sdata[tid] = v;
    __syncthreads();
    for (int off = 1; off < 512; off <<= 1) {
        int t = (tid >= off) ? sdata[tid - off] : 0;
        __syncthreads();
        sdata[tid] += t;
        __syncthreads();
    }
    if (tid < nb) boff[tid] = sdata[tid] - v;       // exclusive
    if (tid == 511) *total_out = sdata[511];        // grand total -> offsets[n]
}

// level 2: one 512-thread workgroup per bucket (512 nodes, 1 node/thread).
// LDS hist -> offsets+dinv; LDS cursor scatter into contiguous csr window.
__global__ void __launch_bounds__(512)
level2_csr(const unsigned* __restrict__ bucket, const int* __restrict__ bcursor,
           const int* __restrict__ boff, int n,
           int* __restrict__ offsets, float* __restrict__ dinv, int* __restrict__ csr) {
    __shared__ int hist[NPB];       // 512
    __shared__ int nodeoff[NPB];
    __shared__ int sdata[NPB];
    int b = blockIdx.x;
    int t = threadIdx.x;            // 0..511, owns node nbeg+t
    int nbeg = b << BBITS;
    int cnt = min(bcursor[b], BCAP);
    int base = boff[b];
    const unsigned* __restrict__ bk = bucket + (size_t)b * BCAP;

    hist[t] = 0;
    __syncthreads();
    for (int e = t; e < cnt; e += 512) atomicAdd(&hist[bk[e] >> 17], 1);
    __syncthreads();
    int h = hist[t];
    sdata[t] = h;
    __syncthreads();
    for (int off = 1; off < NPB; off <<= 1) {
        int v = (t >= off) ? sdata[t - off] : 0;
        __syncthreads();
        sdata[t] += v;
        __syncthreads();
    }
    int p = base + sdata[t] - h;                 // exclusive offset for node nbeg+t
    nodeoff[t] = p;
    int node = nbeg + t;
    if (node < n) {
        offsets[node] = p;
        dinv[node] = rsqrtf((float)(h + 1));     // +1 self-loop; deg>=1 always
    }
    __syncthreads();
    hist[t] = 0;                                 // reuse as cursors
    __syncthreads();
    for (int e = t; e < cnt; e += 512) {
        unsigned w = bk[e];
        int l = w >> 17;
        int pos = nodeoff[l] + atomicAdd(&hist[l], 1);
        csr[pos] = (int)(w & 0x1FFFFu);
    }
}

// ---------------- W -> packed bf16 ----------------
__global__ void convert_w(const void* __restrict__ Wv, unsigned* __restrict__ Wp,
                          int total_pairs, const int* __restrict__ flags) {
    int idx = blockIdx.x * blockDim.x + threadIdx.x;
    if (idx >= total_pairs) return;
    if (flags[2]) {
        Wp[idx] = ((const unsigned*)Wv)[idx];
    } else {
        float2 v = ((const float2*)Wv)[idx];
        Wp[idx] = pack2bf(v.x, v.y);
    }
}

// ---------------- up-front projection: y[node][64] = dinv[node] * (x_row . W_col) ----------------
// A = W rows (M-tile per wave: outcols wave*16..+15), B = node rows (N = 16 nodes/block).
// D row=(lane>>4)*4+reg -> outcol, D col=lane&15 -> node  [m89-verified C/D layout].
// x is converted fp32->bf16 in an LDS tile (stride 68 dwords: 16B-aligned rows, 2-way banks = free).
__global__ void __launch_bounds__(256)
project_mfma(const void* __restrict__ xv, const unsigned* __restrict__ Wp,
             const float* __restrict__ dinv, unsigned* __restrict__ y,
             int n, const int* __restrict__ flags) {
    __shared__ unsigned xs[16][68];
    int t = threadIdx.x;
    int wave = t >> 6;               // outcol tile 0..3
    int lane = t & 63;
    int m16  = lane & 15;
    int quad = lane >> 4;
    int row0 = blockIdx.x * 16;
    if (row0 >= n) return;
    int fx = flags[0];

    // stage 16 node rows as packed bf16 into LDS (converted once, shared by 4 waves)
    for (int idx = t; idx < 16 * 64; idx += 256) {
        int r = idx >> 6, p = idx & 63;
        int node = min(row0 + r, n - 1);
        unsigned w;
        if (fx) {
            w = ((const unsigned*)xv)[(size_t)node * 64 + p];
        } else {
            float2 v = ((const float2*)xv)[(size_t)node * 64 + p];
            w = pack2bf(v.x, v.y);
        }
        xs[r][p] = w;
    }
    __syncthreads();

    const uint4* __restrict__ Arow = (const uint4*)(Wp + (size_t)(wave * 16 + m16) * 64);
    floatx4 acc = {0.f, 0.f, 0.f, 0.f};
#pragma unroll
    for (int kc = 0; kc < 4; ++kc) {
        union { uint4 u; short8 s; } a, b;
        a.u = Arow[kc * 4 + quad];
        b.u = *(const uint4*)&xs[m16][(kc * 4 + quad) * 4];
        acc = __builtin_amdgcn_mfma_f32_16x16x32_bf16(a.s, b.s, acc, 0, 0, 0);
    }
    int node = row0 + m16;
    if (node < n) {
        float di = dinv[node];
        uint2 w;
        w.x = pack2bf(di * acc[0], di * acc[1]);
        w.y = pack2bf(di * acc[2], di * acc[3]);
        *(uint2*)(y + (size_t)node * 32 + wave * 8 + quad * 2) = w;   // outcols wave*16+quad*4..+3
    }
}

// ---------------- propagation on 64-feat pre-scaled rows ----------------
// g[j] = dinv[j]*h[j] is stored; per hop: sum_{j in N(i)+self} g[j], then
//   mode 0: g_out = di^2 * sum (bf16)      mode 1: h_out = di*sum + b (fp32 to d_out)
// wave = 1 node; 16 lanes = 1 edge (uint2/lane = 128B row) -> 4 edge-groups/wave,
// unroll x4 => 16 gathers in flight => one latency round for a deg-16 node.
__global__ void __launch_bounds__(256)
propagate64(const unsigned* __restrict__ hin, const int* __restrict__ offsets,
            const int* __restrict__ csr, const float* __restrict__ dinv,
            void* __restrict__ outv, const void* __restrict__ bv,
            int n, int mode, const int* __restrict__ flags) {
    int wave = threadIdx.x >> 6;
    int lane = threadIdx.x & 63;
    int g    = lane >> 4;            // edge-group 0..3
    int s    = lane & 15;            // dword pair within row (dwords 2s, 2s+1 = feats 4s..4s+3)
    int i = blockIdx.x * 4 + wave;
    if (i >= n) return;
    int beg = offsets[i];
    int end = offsets[i + 1];
    // self row: issue early, same addr across groups (broadcast-friendly)
    uint2 ps = *(const uint2*)(hin + (size_t)i * 32 + 2 * s);
    float a0 = 0.f, a1 = 0.f, a2 = 0.f, a3 = 0.f;
    int k = beg + g;
    for (; k + 12 < end; k += 16) {          // 16 edges per wave per round
        int s0 = csr[k], s1 = csr[k + 4], s2 = csr[k + 8], s3 = csr[k + 12];
        uint2 p0 = *(const uint2*)(hin + (size_t)s0 * 32 + 2 * s);
        uint2 p1 = *(const uint2*)(hin + (size_t)s1 * 32 + 2 * s);
        uint2 p2 = *(const uint2*)(hin + (size_t)s2 * 32 + 2 * s);
        uint2 p3 = *(const uint2*)(hin + (size_t)s3 * 32 + 2 * s);
        a0 += bflo(p0.x); a1 += bfhi(p0.x); a2 += bflo(p0.y); a3 += bfhi(p0.y);
        a0 += bflo(p1.x); a1 += bfhi(p1.x); a2 += bflo(p1.y); a3 += bfhi(p1.y);
        a0 += bflo(p2.x); a1 += bfhi(p2.x); a2 += bflo(p2.y); a3 += bfhi(p2.y);
        a0 += bflo(p3.x); a1 += bfhi(p3.x); a2 += bflo(p3.y); a3 += bfhi(p3.y);
    }
    for (; k < end; k += 4) {
        int sj = csr[k];
        uint2 p = *(const uint2*)(hin + (size_t)sj * 32 + 2 * s);
        a0 += bflo(p.x); a1 += bfhi(p.x); a2 += bflo(p.y); a3 += bfhi(p.y);
    }
    if (g == 0) {                    // self-loop term counted exactly once
        a0 += bflo(ps.x); a1 += bfhi(ps.x); a2 += bflo(ps.y); a3 += bfhi(ps.y);
    }
    // reduce across the 4 edge-groups
    a0 += __shfl_xor(a0, 16); a1 += __shfl_xor(a1, 16);
    a2 += __shfl_xor(a2, 16); a3 += __shfl_xor(a3, 16);
    a0 += __shfl_xor(a0, 32); a1 += __shfl_xor(a1, 32);
    a2 += __shfl_xor(a2, 32); a3 += __shfl_xor(a3, 32);
    if (g == 0) {
        float di = dinv[i];
        if (mode == 0) {
            float sc = di * di;
            uint2 w;
            w.x = pack2bf(sc * a0, sc * a1);
            w.y = pack2bf(sc * a2, sc * a3);
            *(uint2*)((unsigned*)outv + (size_t)i * 32 + 2 * s) = w;
        } else {
            float b0, b1, b2, b3;
            if (flags[2]) {
                const unsigned short* bp = (const unsigned short*)bv;
                union { unsigned u; float f; } c0, c1, c2, c3;
                c0.u = (unsigned)bp[4 * s]     << 16;
                c1.u = (unsigned)bp[4 * s + 1] << 16;
                c2.u = (unsigned)bp[4 * s + 2] << 16;
                c3.u = (unsigned)bp[4 * s + 3] << 16;
                b0 = c0.f; b1 = c1.f; b2 = c2.f; b3 = c3.f;
            } else {
                float4 bb = ((const float4*)bv)[s];
                b0 = bb.x; b1 = bb.y; b2 = bb.z; b3 = bb.w;
            }
            float4 o;
            o.x = di * a0 + b0;
            o.y = di * a1 + b1;
            o.z = di * a2 + b2;
            o.w = di * a3 + b3;
            ((float4*)outv)[(size_t)i * 16 + s] = o;
        }
    }
}

// ---------------- launch ----------------

extern "C" void kernel_launch(void* const* d_in, const int* in_sizes, int n_in,
                              void* d_out, int out_size, void* d_ws, size_t ws_size,
                              hipStream_t stream) {
    const void* x  = d_in[0];
    const int*  ei = (const int*)d_in[1];
    const void* W  = d_in[2];
    const void* b  = d_in[3];
    float* out = (float*)d_out;              // fp32 output

    const int n = in_sizes[0] / FEAT;        // 100000
    const int E = in_sizes[1] / 2;           // 1600000
    const int nbuck = (n + NPB - 1) >> BBITS;   // 196 <= 256

    // workspace layout (256B-aligned slabs)
    char* ws = (char*)d_ws;
    size_t off = 0;
    auto alloc = [&](size_t bytes) {
        void* p = ws + off;
        off = (off + bytes + 255) & ~(size_t)255;
        return p;
    };
    unsigned* y       = (unsigned*)alloc((size_t)n * 32 * sizeof(unsigned));  // 64-feat bf16 rows
    unsigned* hA      = (unsigned*)alloc((size_t)n * 32 * sizeof(unsigned));
    unsigned* Wp      = (unsigned*)alloc((size_t)OUTF * (FEAT / 2) * sizeof(unsigned));
    int*      offsets = (int*)alloc((size_t)(n + 1) * sizeof(int));
    float*    dinv    = (float*)alloc((size_t)n * sizeof(float));
    int*      csr     = (int*)alloc((size_t)E * sizeof(int));
    unsigned* bucket  = (unsigned*)alloc((size_t)nbuck * BCAP * sizeof(unsigned));
    int*      bcursor = (int*)alloc((size_t)nbuck * sizeof(int));
    int*      boff    = (int*)alloc((size_t)nbuck * sizeof(int));
    int*      flags   = (int*)alloc(3 * sizeof(int));

    // dtype sniff (device-side; graph-safe)
    sniff<<<1, 256, 0, stream>>>((const unsigned*)x, (const unsigned*)ei,
                                 (const unsigned*)W, flags);

    // CSR build: LDS-binned two-level
    zero_ints<<<1, 256, 0, stream>>>(bcursor, nbuck);
    level1_bin<<<(E + L1_CHUNK - 1) / L1_CHUNK, 256, 0, stream>>>(ei, E, bcursor, bucket,
                                                                  flags, nbuck);
    scan_bsums<<<1, 512, 0, stream>>>(bcursor, nbuck, boff, &offsets[n]);
    level2_csr<<<nbuck, 512, 0, stream>>>(bucket, bcursor, boff, n, offsets, dinv, csr);

    // W -> bf16 packed
    convert_w<<<(OUTF * FEAT / 2 + 255) / 256, 256, 0, stream>>>(W, Wp, OUTF * FEAT / 2, flags);

    // project first: y = dinv * (x @ W^T)   [(A^3 x) W^T == A^3 (x W^T)]
    project_mfma<<<(n + 15) / 16, 256, 0, stream>>>(x, Wp, dinv, y, n, flags);

    // 3 hops on 64-feat rows: y -> hA -> y -> out (last hop adds bias, writes fp32)
    const int propBlocks = (n + 3) / 4;      // 4 waves/block, 1 node/wave
    propagate64<<<propBlocks, 256, 0, stream>>>(y,  offsets, csr, dinv, hA,  b, n, 0, flags);
    propagate64<<<propBlocks, 256, 0, stream>>>(hA, offsets, csr, dinv, y,   b, n, 0, flags);
    propagate64<<<propBlocks, 256, 0, stream>>>(y,  offsets, csr, dinv, out, b, n, 1, flags);
}